// Round 4
// baseline (85.101 us; speedup 1.0000x reference)
//
#include <hip/hip_runtime.h>
#include <hip/hip_bf16.h>
#include <math.h>

// Symmetric Hausdorff, B=8, N=M=4096, D=2, fp32.
// Round 4: hk_partial was LDS-pipe-bound (2 ds_read_b128 per 160-cyc window
// x 16 waves/CU oversubscribes the shared LDS pipe ~2x). The q-stream is
// wave-uniform, so read it straight from global with a uniform index -> the
// compiler emits s_load (constant cache), freeing the LDS pipe completely.
// |q|^2 is computed per-wave in 2 VALU, arranged so every v_fma reads <=1
// SGPR (qq lives in a VGPR). 3.0 VALU ops/pair -> ~10 us issue floor.
// Pipeline: hk_partial (1024 blocks) -> hk_maxred (256) -> hk_final (1).
// The ~41 us fillBuffer in the profile is the harness poisoning the 256 MiB
// workspace inside the timed window — fixed cost, not ours.

#define B 8
#define N 4096
#define TPB 256
#define IB 4             // i-points per thread
#define JC 16            // j-chunks per (b,dir)
#define JTILE (N / JC)   // 256 j-points per block
#define ITILES (N / TPB) // 16 i-tiles for the reduce stage

__global__ __launch_bounds__(TPB) void hk_partial(const float* __restrict__ pred,
                                                  const float* __restrict__ target,
                                                  float* __restrict__ pw) {
    const int bx  = blockIdx.x;        // 0..63: [ib: 0..3] x [jc: 0..15]
    const int ib  = bx & 3;
    const int jc  = bx >> 2;
    const int b   = blockIdx.y;
    const int dir = blockIdx.z;

    const float2* __restrict__ P =
        reinterpret_cast<const float2*>(dir == 0 ? pred : target) + (size_t)b * N;
    const float2* __restrict__ Q =
        reinterpret_cast<const float2*>(dir == 0 ? target : pred) + (size_t)b * N + jc * JTILE;

    // This thread's IB source points (strided by TPB so pw stores coalesce).
    float m2x[IB], m2y[IB], pp[IB], mn[IB];
    const int i0 = ib * (TPB * IB) + threadIdx.x;
    #pragma unroll
    for (int k = 0; k < IB; ++k) {
        float2 p = P[i0 + k * TPB];
        m2x[k] = -2.f * p.x;
        m2y[k] = -2.f * p.y;
        pp[k]  = fmaf(p.x, p.x, p.y * p.y);
        mn[k]  = 3.402823466e38f;
    }

    // min_j(|q|^2 - 2 p.q). Q[j] is wave-uniform -> scalar loads through the
    // constant cache (no LDS, no staging barrier). j in pairs for v_min3_f32.
    #pragma unroll 4
    for (int j = 0; j < JTILE; j += 2) {
        float2 qa = Q[j];
        float2 qb = Q[j + 1];
        float qqa = fmaf(qa.x, qa.x, qa.y * qa.y);   // lands in VGPR
        float qqb = fmaf(qb.x, qb.x, qb.y * qb.y);
        #pragma unroll
        for (int k = 0; k < IB; ++k) {
            float ta = fmaf(m2x[k], qa.x, fmaf(m2y[k], qa.y, qqa));
            float tb = fmaf(m2x[k], qb.x, fmaf(m2y[k], qb.y, qqb));
            mn[k] = fminf(mn[k], fminf(ta, tb));
        }
    }

    // Partial min for this j-chunk, |p|^2 restored. Layout: [dir][b][jc][i].
    float* dst = pw + (size_t)((dir * B + b) * JC + jc) * N;
    #pragma unroll
    for (int k = 0; k < IB; ++k)
        dst[i0 + k * TPB] = mn[k] + pp[k];
}

// One block per (i-tile, b, dir): min over 16 jc (coalesced), block max-reduce,
// write to a private slot — no atomics, no init required.
__global__ __launch_bounds__(TPB) void hk_maxred(const float* __restrict__ pw,
                                                 float* __restrict__ pw2) {
    const int tile = blockIdx.x;
    const int b    = blockIdx.y;
    const int dir  = blockIdx.z;
    const int t    = threadIdx.x;

    const float* base = pw + (size_t)((dir * B + b) * JC) * N + tile * TPB + t;
    float mnv = base[0];
    #pragma unroll
    for (int jc = 1; jc < JC; ++jc) mnv = fminf(mnv, base[(size_t)jc * N]);

    float mx = mnv;
    #pragma unroll
    for (int off = 32; off > 0; off >>= 1)
        mx = fmaxf(mx, __shfl_down(mx, off, 64));

    __shared__ float sred[TPB / 64];
    if ((t & 63) == 0) sred[t >> 6] = mx;
    __syncthreads();
    if (t == 0) {
        float bm = sred[0];
        #pragma unroll
        for (int w = 1; w < TPB / 64; ++w) bm = fmaxf(bm, sred[w]);
        pw2[(dir * B + b) * ITILES + tile] = bm;   // [dir][b][tile]
    }
}

// Single block: 256 slots -> 16 (dir,b) maxes -> mean over b of sqrt(max(dirs)).
__global__ __launch_bounds__(64) void hk_final(const float* __restrict__ pw2,
                                               float* __restrict__ out) {
    const int t = threadIdx.x;
    __shared__ float h2[2 * B];
    if (t < 2 * B) {
        float mx = pw2[t * ITILES];
        #pragma unroll
        for (int k = 1; k < ITILES; ++k) mx = fmaxf(mx, pw2[t * ITILES + k]);
        h2[t] = mx;
    }
    __syncthreads();
    if (t == 0) {
        float s = 0.f;
        #pragma unroll
        for (int b = 0; b < B; ++b)
            s += sqrtf(fmaxf(fmaxf(h2[b], h2[B + b]), 0.f));
        out[0] = s * (1.0f / B);
    }
}

extern "C" void kernel_launch(void* const* d_in, const int* in_sizes, int n_in,
                              void* d_out, int out_size, void* d_ws, size_t ws_size,
                              hipStream_t stream) {
    const float* pred   = (const float*)d_in[0];
    const float* target = (const float*)d_in[1];
    float* out = (float*)d_out;
    float* pw  = (float*)d_ws;                       // 2*8*16*4096 floats = 4 MB
    float* pw2 = (float*)((char*)d_ws + (size_t)2 * B * JC * N * sizeof(float)); // 256 floats

    dim3 g1(64, B, 2);           // 1024 blocks -> 4 blocks/CU, 16 waves/CU
    hk_partial<<<g1, TPB, 0, stream>>>(pred, target, pw);
    dim3 g2(ITILES, B, 2);       // 256 blocks
    hk_maxred<<<g2, TPB, 0, stream>>>(pw, pw2);
    hk_final<<<1, 64, 0, stream>>>(pw2, out);
}

// Round 5
// 76.976 us; speedup vs baseline: 1.1056x; 1.1056x over previous
//
#include <hip/hip_runtime.h>
#include <hip/hip_bf16.h>
#include <math.h>

// Symmetric Hausdorff, B=8, N=M=4096, D=2, fp32.
// Round 5: revert Round-4's scalar-load attempt (LLVM won't scalarize
// non-invariant loads -> per-lane VMEM, regressed). Back to LDS staging,
// fixing the real Round-3 bottleneck (LDS pipe ~2x oversubscribed):
//   - IB 4->8: each LDS read feeds 8 independent min chains.
//   - 2 q-points packed per ds_read_b128 (qax,qay,qbx,qby); |q|^2 recomputed
//     in VALU (4 inst / 2 points) instead of staged.
//   => per j-iter: 1 ds_read_b128 + 44 VALU  -> LDS pipe at ~55%, VALU-bound,
//      2.75 ops/pair, issue floor ~9.4 us.
//   - JC 16->32 keeps 1024 blocks (4 blocks/CU, 16 waves/CU).
// Pipeline: hk_partial (1024) -> hk_maxred (256) -> hk_final (1).
// The ~41 us fillBuffer in every profile is the harness poisoning the
// 256 MiB workspace inside the timed window — fixed cost, not ours.

#define B 8
#define N 4096
#define TPB 256
#define IB 8              // i-points per thread
#define JC 32             // j-chunks per (b,dir)
#define JTILE (N / JC)    // 128 j-points per block
#define ITILES (N / TPB)  // 16 i-tiles for the reduce stage

__global__ __launch_bounds__(TPB) void hk_partial(const float* __restrict__ pred,
                                                  const float* __restrict__ target,
                                                  float* __restrict__ pw) {
    const int bx  = blockIdx.x;        // 0..63: [ib: 0..1] x [jc: 0..31]
    const int ib  = bx & 1;
    const int jc  = bx >> 1;
    const int b   = blockIdx.y;
    const int dir = blockIdx.z;

    const float2* __restrict__ P =
        reinterpret_cast<const float2*>(dir == 0 ? pred : target) + (size_t)b * N;
    const float*  __restrict__ Qf =
        (dir == 0 ? target : pred) + (size_t)b * N * 2 + (size_t)jc * JTILE * 2;

    // Stage this block's 128 j-points as 64 float4 (2 points each). 1 KB LDS.
    __shared__ float4 sQ[JTILE / 2];
    if (threadIdx.x < JTILE / 2)
        sQ[threadIdx.x] = reinterpret_cast<const float4*>(Qf)[threadIdx.x];
    __syncthreads();

    // This thread's IB source points (strided by TPB so pw stores coalesce).
    float m2x[IB], m2y[IB], pp[IB], mn[IB];
    const int i0 = ib * (TPB * IB) + threadIdx.x;
    #pragma unroll
    for (int k = 0; k < IB; ++k) {
        float2 p = P[i0 + k * TPB];
        m2x[k] = -2.f * p.x;
        m2y[k] = -2.f * p.y;
        pp[k]  = fmaf(p.x, p.x, p.y * p.y);
        mn[k]  = 3.402823466e38f;
    }

    // min_j(|q|^2 - 2 p.q): per iter 1 broadcast b128 (2 points) + 44 VALU.
    #pragma unroll 4
    for (int j = 0; j < JTILE / 2; ++j) {
        float4 q = sQ[j];
        float qqa = fmaf(q.x, q.x, q.y * q.y);
        float qqb = fmaf(q.z, q.z, q.w * q.w);
        #pragma unroll
        for (int k = 0; k < IB; ++k) {
            float ta = fmaf(m2x[k], q.x, fmaf(m2y[k], q.y, qqa));
            float tb = fmaf(m2x[k], q.z, fmaf(m2y[k], q.w, qqb));
            mn[k] = fminf(mn[k], fminf(ta, tb));   // v_min3_f32
        }
    }

    // Partial min for this j-chunk, |p|^2 restored. Layout: [dir][b][jc][i].
    float* dst = pw + (size_t)((dir * B + b) * JC + jc) * N;
    #pragma unroll
    for (int k = 0; k < IB; ++k)
        dst[i0 + k * TPB] = mn[k] + pp[k];
}

// One block per (i-tile, b, dir): min over 32 jc (coalesced), block max-reduce,
// write to a private slot — no atomics, no init required.
__global__ __launch_bounds__(TPB) void hk_maxred(const float* __restrict__ pw,
                                                 float* __restrict__ pw2) {
    const int tile = blockIdx.x;
    const int b    = blockIdx.y;
    const int dir  = blockIdx.z;
    const int t    = threadIdx.x;

    const float* base = pw + (size_t)((dir * B + b) * JC) * N + tile * TPB + t;
    float mnv = base[0];
    #pragma unroll
    for (int jc = 1; jc < JC; ++jc) mnv = fminf(mnv, base[(size_t)jc * N]);

    float mx = mnv;
    #pragma unroll
    for (int off = 32; off > 0; off >>= 1)
        mx = fmaxf(mx, __shfl_down(mx, off, 64));

    __shared__ float sred[TPB / 64];
    if ((t & 63) == 0) sred[t >> 6] = mx;
    __syncthreads();
    if (t == 0) {
        float bm = sred[0];
        #pragma unroll
        for (int w = 1; w < TPB / 64; ++w) bm = fmaxf(bm, sred[w]);
        pw2[(dir * B + b) * ITILES + tile] = bm;   // [dir][b][tile]
    }
}

// Single block: 256 slots -> 16 (dir,b) maxes -> mean over b of sqrt(max(dirs)).
__global__ __launch_bounds__(64) void hk_final(const float* __restrict__ pw2,
                                               float* __restrict__ out) {
    const int t = threadIdx.x;
    __shared__ float h2[2 * B];
    if (t < 2 * B) {
        float mx = pw2[t * ITILES];
        #pragma unroll
        for (int k = 1; k < ITILES; ++k) mx = fmaxf(mx, pw2[t * ITILES + k]);
        h2[t] = mx;
    }
    __syncthreads();
    if (t == 0) {
        float s = 0.f;
        #pragma unroll
        for (int b = 0; b < B; ++b)
            s += sqrtf(fmaxf(fmaxf(h2[b], h2[B + b]), 0.f));
        out[0] = s * (1.0f / B);
    }
}

extern "C" void kernel_launch(void* const* d_in, const int* in_sizes, int n_in,
                              void* d_out, int out_size, void* d_ws, size_t ws_size,
                              hipStream_t stream) {
    const float* pred   = (const float*)d_in[0];
    const float* target = (const float*)d_in[1];
    float* out = (float*)d_out;
    float* pw  = (float*)d_ws;                       // 2*8*32*4096 floats = 8 MB
    float* pw2 = (float*)((char*)d_ws + (size_t)2 * B * JC * N * sizeof(float)); // 256 floats

    dim3 g1(64, B, 2);           // 1024 blocks -> 4 blocks/CU, 16 waves/CU
    hk_partial<<<g1, TPB, 0, stream>>>(pred, target, pw);
    dim3 g2(ITILES, B, 2);       // 256 blocks
    hk_maxred<<<g2, TPB, 0, stream>>>(pw, pw2);
    hk_final<<<1, 64, 0, stream>>>(pw2, out);
}